// Round 14
// baseline (33.334 us; speedup 1.0000x reference)
//
#include <hip/hip_runtime.h>
#include <hip/hip_fp16.h>
#include <math.h>

// QFF1 R14 = R12 geometry (TB=512, PPB=256 h-split, 64000 B LDS -> 2
// blocks/CU) + R7-proven register prefetch (5 float4 scalars at 512 threads
// -- the ONE prefetch configuration that never spilled) + wave-uniform
// sin/cos split.
// Rules:
//   RULE A (R3/R5/R8): outputs leave registers immediately each freq (LDS dmp).
//   RULE B (R2/R4/R6): all 48 channels aggregated in LDS, full-line nt stores.
//   RULE D (R10/R11):  cross-barrier register staging ONLY in the R7 shape:
//                      512 threads x 5 float4 named values.
// Layout: tables fp16 [m][q][40 halves] (80-B rows; 16B chunk jc of row q in
// bank-group (5q+jc)&7, 5 coprime 8); dmp fp16 stride-25 half2 (gcd(25,32)=1,
// 2-way on writes = free per m136).

constexpr int N_POINTS = 131072;
constexpr int NFREQ    = 6;
constexpr int QN       = 80;
constexpr int CRN      = 32;     // NUM_FEATS(4) * NUM_CORRS(8)
constexpr int M_PER_F  = 6;      // {sin,cos} x 3 dims
constexpr int ROW      = 40;                 // halves per q-row (80 B)
constexpr int MSTRIDE  = QN * ROW;           // 3200 halves per table
constexpr int TSTRIDE  = CRN * QN;           // 2560 floats per src table
constexpr int FH       = M_PER_F * MSTRIDE;  // 19200 halves per freq
constexpr int FH4      = FH / 8;             // 2400 float4 per freq table
constexpr int NTAB     = NFREQ * M_PER_F;    // 36 tables
constexpr int TB       = 512;                // threads per block
constexpr int PPB      = 256;                // points per block (h-split)
constexpr int NBLK     = N_POINTS / PPB;     // 512 blocks -> 2 resident/CU
constexpr int DSTR     = 25;                 // dmp stride in half2
constexpr size_t TAB_BYTES = (size_t)NTAB * MSTRIDE * 2;   // 230400 B

typedef float f32x4 __attribute__((ext_vector_type(4)));

// ---------------- prep: transpose + pad + fp16 ----------------
__global__ __launch_bounds__(256)
void qff1_prep(const float* __restrict__ qff, __half* __restrict__ wsh)
{
    int i = blockIdx.x * 256 + threadIdx.x;        // over 36*2560 src elements
    if (i >= NTAB * TSTRIDE) return;
    int T  = i / TSTRIDE;
    int r  = i - T * TSTRIDE;
    int cr = r / QN;
    int q  = r - cr * QN;
    wsh[T * MSTRIDE + q * ROW + cr] = __float2half(qff[i]);
}

// ---------------- main ----------------
__global__ __launch_bounds__(TB, 4)   // cap VGPR at 128: guarantee 2 blocks/CU
void qff1_main(const float* __restrict__ points,
               const __half* __restrict__ wsh,
               const float* __restrict__ freqs,
               float4* __restrict__ out4)
{
    __shared__ __align__(16) __half  tab[FH];          // 38400 B
    __shared__ __align__(16) __half2 dmp2[PPB * DSTR]; // 25600 B -> 64000

    const int tid = threadIdx.x;
    const int p   = tid & (PPB - 1);
    const int h   = tid >> 8;            // wave-uniform: waves 0-3 sin, 4-7 cos
    const int n   = blockIdx.x * PPB + p;

    const float px = points[n * 3 + 0];
    const float py = points[n * 3 + 1];
    const float pz = points[n * 3 + 2];

    const int i4 = tid + 4 * TB;         // partial tail (2400 = 4*512 + 352)

    // prologue: stage table 0 (serial, latency exposed once)
    {
        const float4* src = reinterpret_cast<const float4*>(wsh);
        float4* dst = reinterpret_cast<float4*>(tab);
        dst[tid]          = src[tid];
        dst[tid + TB]     = src[tid + TB];
        dst[tid + 2 * TB] = src[tid + 2 * TB];
        dst[tid + 3 * TB] = src[tid + 3 * TB];
        if (i4 < FH4) dst[i4] = src[i4];
    }
    __syncthreads();

    for (int f = 0; f < NFREQ; ++f) {
        const bool more = (f + 1 < NFREQ);

        // R7-pattern prefetch: 5 named float4s, issued before compute,
        // committed by ds_write after the read barrier.
        float4 sv0, sv1, sv2, sv3, sv4;
        if (more) {
            const float4* src =
                reinterpret_cast<const float4*>(wsh + (size_t)(f + 1) * FH);
            sv0 = src[tid];
            sv1 = src[tid + TB];
            sv2 = src[tid + 2 * TB];
            sv3 = src[tid + 3 * TB];
            if (i4 < FH4) sv4 = src[i4];
        }

        const float freq = freqs[f];

        // wave-uniform half: compute only the needed transcendental
        float e0, e1, e2;
        if (h == 0) {
            e0 = __sinf(px * freq); e1 = __sinf(py * freq); e2 = __sinf(pz * freq);
        } else {
            e0 = __cosf(px * freq); e1 = __cosf(py * freq); e2 = __cosf(pz * freq);
        }

        int b0[3], b1[3];
        __half2 w2[3];
        float ee[3] = { e0, e1, e2 };
#pragma unroll
        for (int d = 0; d < 3; ++d) {
            float pos = (ee[d] + 1.0f) * (0.5f * (float)(QN - 1));
            float fi  = floorf(pos);
            int q0    = (int)fi;
            q0 = q0 < 0 ? 0 : (q0 > QN - 1 ? QN - 1 : q0);
            int q1 = q0 + 1; if (q1 > QN - 1) q1 = QN - 1;
            w2[d] = __float2half2_rn(pos - (float)q0);
            int m = h * 3 + d;
            b0[d] = m * MSTRIDE + q0 * ROW;
            b1[d] = m * MSTRIDE + q1 * ROW;
        }

        float acc[4];
#pragma unroll
        for (int jc = 0; jc < 4; ++jc) {   // feature c=jc, ranks 0..7
            __half2 Lv[3][4];
#pragma unroll
            for (int d = 0; d < 3; ++d) {
                union { float4 v; __half2 hh[4]; } A, B;
                A.v = *(const float4*)&tab[b0[d] + jc * 8];
                B.v = *(const float4*)&tab[b1[d] + jc * 8];
#pragma unroll
                for (int kk = 0; kk < 4; ++kk)
                    Lv[d][kk] = __hfma2(w2[d], __hsub2(B.hh[kk], A.hh[kk]), A.hh[kk]);
            }
            float a = 0.0f;
#pragma unroll
            for (int kk = 0; kk < 4; ++kk) {
                float2 f0 = __half22float2(Lv[0][kk]);
                float2 f1 = __half22float2(Lv[1][kk]);
                float2 f2 = __half22float2(Lv[2][kk]);
                a += f0.x * f1.x * f2.x + f0.y * f1.y * f2.y;
            }
            acc[jc] = a;
        }

        // RULE A: outputs leave registers NOW (disjoint slots per half)
        dmp2[p * DSTR + h * 12 + f * 2 + 0] = __floats2half2_rn(acc[0], acc[1]);
        dmp2[p * DSTR + h * 12 + f * 2 + 1] = __floats2half2_rn(acc[2], acc[3]);

        __syncthreads();   // all reads of table f done

        if (more) {        // commit prefetched table f+1 (short segment)
            float4* dst = reinterpret_cast<float4*>(tab);
            dst[tid]          = sv0;
            dst[tid + TB]     = sv1;
            dst[tid + 2 * TB] = sv2;
            dst[tid + 3 * TB] = sv3;
            if (i4 < FH4) dst[i4] = sv4;
            __syncthreads();
        }
    }

    // epilogue: full-line coalesced nontemporal stores (48 KB/block)
    // float4 c of point pp: c=(f*2+s) -> slot off = (c&1)*12 + (c>>1)*2
    const size_t base = (size_t)blockIdx.x * (PPB * 12);
#pragma unroll
    for (int k = 0; k < 6; ++k) {
        int i  = tid + k * TB;          // 0..3071
        int pp = i / 12;
        int c  = i - pp * 12;
        int off = (c & 1) * 12 + (c >> 1) * 2;
        float2 lo = __half22float2(dmp2[pp * DSTR + off + 0]);
        float2 hi = __half22float2(dmp2[pp * DSTR + off + 1]);
        f32x4 v = { lo.x, lo.y, hi.x, hi.y };
        __builtin_nontemporal_store(v, (f32x4*)&out4[base + i]);
    }
}

// ---------------- fallback (ws too small): R4-style direct ----------------
__global__ __launch_bounds__(512, 8)
void qff1_fallback(const float* __restrict__ points,
                   const float* __restrict__ qff,
                   const float* __restrict__ freqs,
                   float* __restrict__ out)
{
    __shared__ __align__(16) __half tab[FH];
    const int tid = threadIdx.x;
    const int f   = blockIdx.y;

    const float* tsrc = qff + (size_t)f * (M_PER_F * CRN * QN);
    __half2* lds2 = reinterpret_cast<__half2*>(tab);
    for (int idx = tid; idx < M_PER_F * QN * (CRN / 2); idx += 512) {
        int m   = idx / (QN * CRN / 2);
        int rem = idx - m * (QN * CRN / 2);
        int q   = rem >> 4;
        int cr2 = rem & 15;
        float v0 = tsrc[m * (CRN * QN) + (2 * cr2    ) * QN + q];
        float v1 = tsrc[m * (CRN * QN) + (2 * cr2 + 1) * QN + q];
        lds2[m * (MSTRIDE / 2) + q * (ROW / 2) + cr2] = __floats2half2_rn(v0, v1);
    }
    __syncthreads();

    const int n = blockIdx.x * 512 + tid;
    const float px = points[n * 3 + 0];
    const float py = points[n * 3 + 1];
    const float pz = points[n * 3 + 2];
    const float freq = freqs[f];

    float enc[6];
    {
        float s, cc;
        __sincosf(px * freq, &s, &cc); enc[0] = s; enc[3] = cc;
        __sincosf(py * freq, &s, &cc); enc[1] = s; enc[4] = cc;
        __sincosf(pz * freq, &s, &cc); enc[2] = s; enc[5] = cc;
    }
    int b0[6], b1[6];
    __half2 w2[6];
#pragma unroll
    for (int m = 0; m < 6; ++m) {
        float pos = (enc[m] + 1.0f) * (0.5f * (float)(QN - 1));
        float fi  = floorf(pos);
        int q0    = (int)fi;
        q0 = q0 < 0 ? 0 : (q0 > QN - 1 ? QN - 1 : q0);
        int q1 = q0 + 1; if (q1 > QN - 1) q1 = QN - 1;
        w2[m] = __float2half2_rn(pos - (float)q0);
        b0[m] = m * MSTRIDE + q0 * ROW;
        b1[m] = m * MSTRIDE + q1 * ROW;
    }
    float accv[8];
#pragma unroll
    for (int s = 0; s < 2; ++s) {
#pragma unroll
        for (int jc = 0; jc < 4; ++jc) {
            __half2 Lv[3][4];
#pragma unroll
            for (int d = 0; d < 3; ++d) {
                int m = s * 3 + d;
                union { float4 v; __half2 hh[4]; } A, B;
                A.v = *(const float4*)&tab[b0[m] + jc * 8];
                B.v = *(const float4*)&tab[b1[m] + jc * 8];
#pragma unroll
                for (int kk = 0; kk < 4; ++kk)
                    Lv[d][kk] = __hfma2(w2[m], __hsub2(B.hh[kk], A.hh[kk]), A.hh[kk]);
            }
            float a = 0.0f;
#pragma unroll
            for (int kk = 0; kk < 4; ++kk) {
                float2 f0 = __half22float2(Lv[0][kk]);
                float2 f1 = __half22float2(Lv[1][kk]);
                float2 f2 = __half22float2(Lv[2][kk]);
                a += f0.x * f1.x * f2.x + f0.y * f1.y * f2.y;
            }
            accv[s * 4 + jc] = a;
        }
    }
    float4* o = (float4*)(out + (size_t)n * 48 + f * 8);
    o[0] = make_float4(accv[0], accv[1], accv[2], accv[3]);
    o[1] = make_float4(accv[4], accv[5], accv[6], accv[7]);
}

extern "C" void kernel_launch(void* const* d_in, const int* in_sizes, int n_in,
                              void* d_out, int out_size, void* d_ws, size_t ws_size,
                              hipStream_t stream) {
    const float* points = (const float*)d_in[0];   // (131072, 3)
    const float* qff    = (const float*)d_in[1];   // (36, 32, 80, 1)
    const float* freqs  = (const float*)d_in[2];   // (6,)
    float* out = (float*)d_out;                    // (131072, 48)

    if (ws_size >= TAB_BYTES) {
        __half* wsh = (__half*)d_ws;
        qff1_prep<<<dim3((NTAB * TSTRIDE + 255) / 256), dim3(256), 0, stream>>>(qff, wsh);
        qff1_main<<<dim3(NBLK), dim3(TB), 0, stream>>>(points, wsh, freqs, (float4*)out);
    } else {
        qff1_fallback<<<dim3(N_POINTS / 512, NFREQ), dim3(512), 0, stream>>>(points, qff, freqs, out);
    }
}

// Round 15
// 32.190 us; speedup vs baseline: 1.0355x; 1.0355x over previous
//
#include <hip/hip_runtime.h>
#include <hip/hip_fp16.h>
#include <math.h>

// QFF1 R15 = R13 (best: dbuf tables, 1 block/CU, 7 barriers) + R14's
// wave-uniform sin/cos split (h = tid>>9 is wave-uniform -> each wave
// computes only 3 transcendentals per freq, not 6).
// Rules (hard-won):
//   RULE A (R3/R5/R8): outputs leave registers immediately each freq (LDS dmp).
//   RULE B (R2/R4/R6): all 48 channels aggregated in LDS, full-line nt stores.
//   RULE D (R10/R11):  no per-thread arrays across barriers; dbuf staging uses
//                      named float4 scalars consumed within the same phase.
// Layout: tables fp16 [m][q][40 halves] (80-B rows; 16B chunk jc of row q in
// bank-group (5q+jc)&7, 5 coprime 8); dmp fp16 stride-25 half2 (gcd(25,32)=1).
// LDS: tabA+tabB (2x38400) + dmp (51200) = 128000 B -> 1 block/CU, 16 waves.

constexpr int N_POINTS = 131072;
constexpr int NFREQ    = 6;
constexpr int QN       = 80;
constexpr int CRN      = 32;     // NUM_FEATS(4) * NUM_CORRS(8)
constexpr int M_PER_F  = 6;      // {sin,cos} x 3 dims
constexpr int ROW      = 40;                 // halves per q-row (80 B)
constexpr int MSTRIDE  = QN * ROW;           // 3200 halves per table
constexpr int TSTRIDE  = CRN * QN;           // 2560 floats per src table
constexpr int FH       = M_PER_F * MSTRIDE;  // 19200 halves per freq
constexpr int FH4      = FH / 8;             // 2400 float4 per freq table
constexpr int NTAB     = NFREQ * M_PER_F;    // 36 tables
constexpr int TB       = 1024;               // threads per block
constexpr int PPB      = 512;                // points per block
constexpr int NBLK     = N_POINTS / PPB;     // 256 blocks = 1/CU
constexpr int DSTR     = 25;                 // dmp stride in half2
constexpr size_t TAB_BYTES = (size_t)NTAB * MSTRIDE * 2;   // 230400 B

typedef float f32x4 __attribute__((ext_vector_type(4)));

// ---------------- prep: transpose + pad + fp16 ----------------
__global__ __launch_bounds__(256)
void qff1_prep(const float* __restrict__ qff, __half* __restrict__ wsh)
{
    int i = blockIdx.x * 256 + threadIdx.x;        // over 36*2560 src elements
    if (i >= NTAB * TSTRIDE) return;
    int T  = i / TSTRIDE;
    int r  = i - T * TSTRIDE;
    int cr = r / QN;
    int q  = r - cr * QN;
    wsh[T * MSTRIDE + q * ROW + cr] = __float2half(qff[i]);
}

// ---------------- main ----------------
__global__ __launch_bounds__(TB, 4)
void qff1_main(const float* __restrict__ points,
               const __half* __restrict__ wsh,
               const float* __restrict__ freqs,
               float4* __restrict__ out4)
{
    __shared__ __align__(16) __half  tabA[FH];          // 38400 B
    __shared__ __align__(16) __half  tabB[FH];          // 38400 B
    __shared__ __align__(16) __half2 dmp2[PPB * DSTR];  // 51200 B -> 128000

    const int tid = threadIdx.x;
    const int p   = tid & (PPB - 1);
    const int h   = tid >> 9;            // wave-uniform: waves 0-7 sin, 8-15 cos
    const int n   = blockIdx.x * PPB + p;

    const float px = points[n * 3 + 0];
    const float py = points[n * 3 + 1];
    const float pz = points[n * 3 + 2];

    const int i0 = tid, i1 = tid + TB, i2 = tid + 2 * TB;   // i2 partial (352)

    // prologue: stage table 0 into tabA
    {
        const float4* src = reinterpret_cast<const float4*>(wsh);
        float4* dst = reinterpret_cast<float4*>(tabA);
        dst[i0] = src[i0];
        dst[i1] = src[i1];
        if (i2 < FH4) dst[i2] = src[i2];
    }
    __syncthreads();

    for (int f = 0; f < NFREQ; ++f) {
        const __half* cur = (f & 1) ? tabB : tabA;
        float4* nxt = reinterpret_cast<float4*>((f & 1) ? tabA : tabB);
        const bool more = (f + 1 < NFREQ);

        // issue-early: next table's loads fly during this phase's compute;
        // consumed by ds_write BEFORE the barrier (no cross-barrier arrays).
        float4 sv0, sv1, sv2;
        if (more) {
            const float4* src =
                reinterpret_cast<const float4*>(wsh + (size_t)(f + 1) * FH);
            sv0 = src[i0];
            sv1 = src[i1];
            if (i2 < FH4) sv2 = src[i2];
        }

        const float freq = freqs[f];

        // wave-uniform half: only the needed transcendental (3 ops, not 6)
        float e0, e1, e2;
        if (h == 0) {
            e0 = __sinf(px * freq); e1 = __sinf(py * freq); e2 = __sinf(pz * freq);
        } else {
            e0 = __cosf(px * freq); e1 = __cosf(py * freq); e2 = __cosf(pz * freq);
        }
        float ee[3] = { e0, e1, e2 };

        int b0[3], b1[3];
        __half2 w2[3];
#pragma unroll
        for (int d = 0; d < 3; ++d) {
            float pos = (ee[d] + 1.0f) * (0.5f * (float)(QN - 1));
            float fi  = floorf(pos);
            int q0    = (int)fi;
            q0 = q0 < 0 ? 0 : (q0 > QN - 1 ? QN - 1 : q0);
            int q1 = q0 + 1; if (q1 > QN - 1) q1 = QN - 1;
            w2[d] = __float2half2_rn(pos - (float)q0);
            int m = h * 3 + d;
            b0[d] = m * MSTRIDE + q0 * ROW;
            b1[d] = m * MSTRIDE + q1 * ROW;
        }

        float acc[4];
#pragma unroll
        for (int jc = 0; jc < 4; ++jc) {   // feature c=jc, ranks 0..7
            __half2 Lv[3][4];
#pragma unroll
            for (int d = 0; d < 3; ++d) {
                union { float4 v; __half2 hh[4]; } A, B;
                A.v = *(const float4*)&cur[b0[d] + jc * 8];
                B.v = *(const float4*)&cur[b1[d] + jc * 8];
#pragma unroll
                for (int kk = 0; kk < 4; ++kk)
                    Lv[d][kk] = __hfma2(w2[d], __hsub2(B.hh[kk], A.hh[kk]), A.hh[kk]);
            }
            float a = 0.0f;
#pragma unroll
            for (int kk = 0; kk < 4; ++kk) {
                float2 f0 = __half22float2(Lv[0][kk]);
                float2 f1 = __half22float2(Lv[1][kk]);
                float2 f2 = __half22float2(Lv[2][kk]);
                a += f0.x * f1.x * f2.x + f0.y * f1.y * f2.y;
            }
            acc[jc] = a;
        }

        // RULE A: outputs leave registers NOW (disjoint slots per half)
        dmp2[p * DSTR + h * 12 + f * 2 + 0] = __floats2half2_rn(acc[0], acc[1]);
        dmp2[p * DSTR + h * 12 + f * 2 + 1] = __floats2half2_rn(acc[2], acc[3]);

        // write-late (same phase): install table f+1 into the idle buffer
        if (more) {
            nxt[i0] = sv0;
            nxt[i1] = sv1;
            if (i2 < FH4) nxt[i2] = sv2;
        }
        __syncthreads();   // reads of cur done; nxt committed
    }

    // epilogue: full-line coalesced nontemporal stores (98 KB/block)
    // float4 c of point pp: c=(f*2+s) -> slot off = (c&1)*12 + (c>>1)*2
    const size_t base = (size_t)blockIdx.x * (PPB * 12);
#pragma unroll
    for (int k = 0; k < 6; ++k) {
        int i  = tid + k * TB;          // 0..6143
        int pp = i / 12;
        int c  = i - pp * 12;
        int off = (c & 1) * 12 + (c >> 1) * 2;
        float2 lo = __half22float2(dmp2[pp * DSTR + off + 0]);
        float2 hi = __half22float2(dmp2[pp * DSTR + off + 1]);
        f32x4 v = { lo.x, lo.y, hi.x, hi.y };
        __builtin_nontemporal_store(v, (f32x4*)&out4[base + i]);
    }
}

// ---------------- fallback (ws too small): R4-style direct ----------------
__global__ __launch_bounds__(512, 8)
void qff1_fallback(const float* __restrict__ points,
                   const float* __restrict__ qff,
                   const float* __restrict__ freqs,
                   float* __restrict__ out)
{
    __shared__ __align__(16) __half tab[FH];
    const int tid = threadIdx.x;
    const int f   = blockIdx.y;

    const float* tsrc = qff + (size_t)f * (M_PER_F * CRN * QN);
    __half2* lds2 = reinterpret_cast<__half2*>(tab);
    for (int idx = tid; idx < M_PER_F * QN * (CRN / 2); idx += 512) {
        int m   = idx / (QN * CRN / 2);
        int rem = idx - m * (QN * CRN / 2);
        int q   = rem >> 4;
        int cr2 = rem & 15;
        float v0 = tsrc[m * (CRN * QN) + (2 * cr2    ) * QN + q];
        float v1 = tsrc[m * (CRN * QN) + (2 * cr2 + 1) * QN + q];
        lds2[m * (MSTRIDE / 2) + q * (ROW / 2) + cr2] = __floats2half2_rn(v0, v1);
    }
    __syncthreads();

    const int n = blockIdx.x * 512 + tid;
    const float px = points[n * 3 + 0];
    const float py = points[n * 3 + 1];
    const float pz = points[n * 3 + 2];
    const float freq = freqs[f];

    float enc[6];
    {
        float s, cc;
        __sincosf(px * freq, &s, &cc); enc[0] = s; enc[3] = cc;
        __sincosf(py * freq, &s, &cc); enc[1] = s; enc[4] = cc;
        __sincosf(pz * freq, &s, &cc); enc[2] = s; enc[5] = cc;
    }
    int b0[6], b1[6];
    __half2 w2[6];
#pragma unroll
    for (int m = 0; m < 6; ++m) {
        float pos = (enc[m] + 1.0f) * (0.5f * (float)(QN - 1));
        float fi  = floorf(pos);
        int q0    = (int)fi;
        q0 = q0 < 0 ? 0 : (q0 > QN - 1 ? QN - 1 : q0);
        int q1 = q0 + 1; if (q1 > QN - 1) q1 = QN - 1;
        w2[m] = __float2half2_rn(pos - (float)q0);
        b0[m] = m * MSTRIDE + q0 * ROW;
        b1[m] = m * MSTRIDE + q1 * ROW;
    }
    float accv[8];
#pragma unroll
    for (int s = 0; s < 2; ++s) {
#pragma unroll
        for (int jc = 0; jc < 4; ++jc) {
            __half2 Lv[3][4];
#pragma unroll
            for (int d = 0; d < 3; ++d) {
                int m = s * 3 + d;
                union { float4 v; __half2 hh[4]; } A, B;
                A.v = *(const float4*)&tab[b0[m] + jc * 8];
                B.v = *(const float4*)&tab[b1[m] + jc * 8];
#pragma unroll
                for (int kk = 0; kk < 4; ++kk)
                    Lv[d][kk] = __hfma2(w2[m], __hsub2(B.hh[kk], A.hh[kk]), A.hh[kk]);
            }
            float a = 0.0f;
#pragma unroll
            for (int kk = 0; kk < 4; ++kk) {
                float2 f0 = __half22float2(Lv[0][kk]);
                float2 f1 = __half22float2(Lv[1][kk]);
                float2 f2 = __half22float2(Lv[2][kk]);
                a += f0.x * f1.x * f2.x + f0.y * f1.y * f2.y;
            }
            accv[s * 4 + jc] = a;
        }
    }
    float4* o = (float4*)(out + (size_t)n * 48 + f * 8);
    o[0] = make_float4(accv[0], accv[1], accv[2], accv[3]);
    o[1] = make_float4(accv[4], accv[5], accv[6], accv[7]);
}

extern "C" void kernel_launch(void* const* d_in, const int* in_sizes, int n_in,
                              void* d_out, int out_size, void* d_ws, size_t ws_size,
                              hipStream_t stream) {
    const float* points = (const float*)d_in[0];   // (131072, 3)
    const float* qff    = (const float*)d_in[1];   // (36, 32, 80, 1)
    const float* freqs  = (const float*)d_in[2];   // (6,)
    float* out = (float*)d_out;                    // (131072, 48)

    if (ws_size >= TAB_BYTES) {
        __half* wsh = (__half*)d_ws;
        qff1_prep<<<dim3((NTAB * TSTRIDE + 255) / 256), dim3(256), 0, stream>>>(qff, wsh);
        qff1_main<<<dim3(NBLK), dim3(TB), 0, stream>>>(points, wsh, freqs, (float4*)out);
    } else {
        qff1_fallback<<<dim3(N_POINTS / 512, NFREQ), dim3(512), 0, stream>>>(points, qff, freqs, out);
    }
}